// Round 6
// baseline (175.864 us; speedup 1.0000x reference)
//
#include <hip/hip_runtime.h>
#include <math.h>

typedef unsigned long long ull;

// Problem constants (from setup_inputs): B=64, G=4999, P=50
constexpr int Bc = 64;
constexpr int Gc = 4999;
constexpr int Pc = 50;

constexpr int SORT_N = 8192;   // pow2 >= G
constexpr int SORT_T = 1024;   // threads per block
constexpr int EPT    = 8;      // sort elements per thread
constexpr int LPW    = 79;     // genes per lane in es phase (ceil(4999/64))
constexpr int SLOTS  = 5056;   // 79*64 chunk-major slots
constexpr ull PADKEY = 0xFFFFFFFFFFFFFFFFull;

__device__ __forceinline__ ull shfl_xor64(ull v, int lm) {
    int lo = __shfl_xor((int)(unsigned)(v & 0xFFFFFFFFull), lm, 64);
    int hi = __shfl_xor((int)(unsigned)(v >> 32), lm, 64);
    return ((ull)(unsigned)hi << 32) | (unsigned)lo;
}

// ---------------------------------------------------------------------------
// ONE kernel, one block per sample b (64 blocks x 1024 threads):
//   phase 0: block packs its OWN private pathway-bitmask copy to global
//            (redundant per block -> zero cross-block communication)
//   phase 1: stable descending argsort of the row: hybrid bitonic
//            (registers + wave shuffles; LDS only for j>=512) - round-2 net
//   phase 2: scatter wq + mask into chunk-major LDS (conflict-free es reads)
//   phase 3: es: wave w computes pathways 4w..4w+3 in ONE pass over its genes
// LDS: 64 KB union (keys <-> smask+swq).
// ---------------------------------------------------------------------------
__global__ __launch_bounds__(SORT_T) void fused_kernel(
    const float* __restrict__ expr, const float* __restrict__ pathway,
    ull* __restrict__ pball, float* __restrict__ out, int B, int P, int G)
{
    __shared__ union {
        ull keys[SORT_N];                               // 65536 B
        struct { ull smask[SLOTS]; float swq[SLOTS]; } es;  // 60672 B
    } lds;

    const int b = blockIdx.x;
    const int tid = threadIdx.x;
    const int base = tid * EPT;
    const float* row = expr + (size_t)b * G;
    ull* pb = pball + (size_t)b * SLOTS;   // this block's private pbits copy

    // ---- Phase 0: pack pathway bits (own copy; global writes drain during sort)
    for (int g = tid; g < G; g += SORT_T) {
        ull m = 0;
#pragma unroll
        for (int p = 0; p < Pc; ++p)
            if (pathway[(size_t)p * G + g] > 0.0f) m |= (1ull << p);
        pb[g] = m;
    }

    // ---- Phase 1: bitonic sort (round-2 verified network) ----
    ull r[EPT];
#pragma unroll
    for (int o = 0; o < EPT; ++o) {
        int i = base + o;
        if (i < G) {
            unsigned u = __float_as_uint(row[i]);
            unsigned m = (u >> 31) ? ~u : (u | 0x80000000u);  // monotone map
            r[o] = ((ull)(~m) << 32) | (unsigned)i;
        } else {
            r[o] = PADKEY;
        }
    }

    // Phase 1a: kk = 2..512 entirely in registers + wave shuffles
#pragma unroll
    for (int kk = 2; kk <= 512; kk <<= 1) {
#pragma unroll
        for (int j = kk >> 1; j >= 8; j >>= 1) {       // lm = j/8 <= 32: intra-wave
            int lm = j >> 3;
            bool lower = ((tid & lm) == 0);
            bool up = ((base & kk) == 0);
            bool takeMin = (lower == up);
#pragma unroll
            for (int o = 0; o < EPT; ++o) {
                ull c = shfl_xor64(r[o], lm);
                ull mn = (r[o] < c) ? r[o] : c;
                ull mx = (r[o] < c) ? c : r[o];
                r[o] = takeMin ? mn : mx;
            }
        }
#pragma unroll
        for (int j = 4; j >= 1; j >>= 1) {
            if (j < kk) {
#pragma unroll
                for (int o = 0; o < EPT; ++o) {
                    if ((o & j) == 0) {
                        bool up = (((base + o) & kk) == 0);
                        ull a = r[o], c = r[o | j];
                        if ((a > c) == up) { r[o] = c; r[o | j] = a; }
                    }
                }
            }
        }
    }

    // Phase 1b: kk = 1024..8192; j>=512 via LDS, tail local
#pragma unroll
    for (int o = 0; o < EPT; ++o) lds.keys[base + o] = r[o];
    __syncthreads();

#pragma unroll
    for (int kk = 1024; kk <= SORT_N; kk <<= 1) {
#pragma unroll
        for (int j = kk >> 1; j >= 512; j >>= 1) {
#pragma unroll
            for (int t = tid; t < SORT_N / 2; t += SORT_T) {
                int i  = ((t & ~(j - 1)) << 1) | (t & (j - 1));
                int ix = i | j;
                ull a = lds.keys[i], c = lds.keys[ix];
                bool up = ((i & kk) == 0);
                if ((a > c) == up) { lds.keys[i] = c; lds.keys[ix] = a; }
            }
            __syncthreads();
        }
#pragma unroll
        for (int o = 0; o < EPT; ++o) r[o] = lds.keys[base + o];
#pragma unroll
        for (int j = 256; j >= 8; j >>= 1) {
            int lm = j >> 3;
            bool lower = ((tid & lm) == 0);
            bool up = ((base & kk) == 0);
            bool takeMin = (lower == up);
#pragma unroll
            for (int o = 0; o < EPT; ++o) {
                ull c = shfl_xor64(r[o], lm);
                ull mn = (r[o] < c) ? r[o] : c;
                ull mx = (r[o] < c) ? c : r[o];
                r[o] = takeMin ? mn : mx;
            }
        }
#pragma unroll
        for (int j = 4; j >= 1; j >>= 1) {
#pragma unroll
            for (int o = 0; o < EPT; ++o) {
                if ((o & j) == 0) {
                    bool up = (((base + o) & kk) == 0);
                    ull a = r[o], c = r[o | j];
                    if ((a > c) == up) { r[o] = c; r[o | j] = a; }
                }
            }
        }
        if (kk < SORT_N) {
#pragma unroll
            for (int o = 0; o < EPT; ++o) lds.keys[base + o] = r[o];
            __syncthreads();
        }
    }

    // all threads done READING keys region before scatter overwrites it
    __syncthreads();

    // ---- Phase 2: scatter wq + mask into chunk-major slots ----
    // rank i owned by es-lane L=i/79 at step k=i%79 -> slot k*64+L
#pragma unroll
    for (int o = 0; o < EPT; ++o) {
        int i = base + o;
        if (i < G) {
            ull k = r[o];
            int idx = (int)(unsigned)(k & 0xFFFFFFFFu);
            unsigned m = ~((unsigned)(k >> 32));
            unsigned absbits = ((m >> 31) ? m : ~m) & 0x7FFFFFFFu;
            float av = __uint_as_float(absbits);
            int slot = (i % LPW) * 64 + (i / LPW);
            lds.es.swq[slot]   = sqrtf(sqrtf(av));   // |v|^0.25
            lds.es.smask[slot] = pb[idx];            // own-block L2-hot gather
        }
    }
    __syncthreads();

    // ---- Phase 3: es. Wave w handles pathways p0..p0+3 in one pass. ----
    const int lane = tid & 63;
    const int w = tid >> 6;
    const int p0 = w * 4;
    if (p0 >= P) return;

    const int start = lane * LPW;
    const int cnt = (start + LPW < G) ? LPW : (G - start);

    // Pass A: per-chunk (sum w*hit, #hit) for 4 pathways at once
    double sw[4] = {0.0, 0.0, 0.0, 0.0};
    int sh[4] = {0, 0, 0, 0};
    for (int k = 0; k < cnt; ++k) {
        int s = k * 64 + lane;
        unsigned nib = (unsigned)((lds.es.smask[s] >> p0) & 15ull);
        double wv = (double)lds.es.swq[s];
#pragma unroll
        for (int q = 0; q < 4; ++q) {
            if ((nib >> q) & 1u) { sw[q] += wv; sh[q]++; }
        }
    }
    double norm[4], inv_denom[4], running[4];
    int sht[4];
#pragma unroll
    for (int q = 0; q < 4; ++q) {
        double swt = sw[q];
        int shq = sh[q];
#pragma unroll
        for (int off = 1; off < 64; off <<= 1) {
            swt += __shfl_xor(swt, off, 64);
            shq += __shfl_xor(shq, off, 64);
        }
        sht[q] = shq;
        norm[q]      = (swt > 0.0) ? 1.0 / swt : 1.0;
        inv_denom[q] = 1.0 / fmax((double)(G - shq), 1.0);
        // chunk sum (algebraic) + wave inclusive scan -> exclusive prefix
        double csum = sw[q] * norm[q] - (double)(cnt - sh[q]) * inv_denom[q];
        double x = csum;
#pragma unroll
        for (int off = 1; off < 64; off <<= 1) {
            double vv = __shfl_up(x, off, 64);
            if (lane >= off) x += vv;
        }
        running[q] = x - csum;
    }

    // Pass C: walk chunk, first-occurrence argmax of |running| (4 pathways)
    double bestv[4] = {-1.0, -1.0, -1.0, -1.0};
    double bestr[4] = {0.0, 0.0, 0.0, 0.0};
    int besti[4] = {0x7FFFFFFF, 0x7FFFFFFF, 0x7FFFFFFF, 0x7FFFFFFF};
    for (int k = 0; k < cnt; ++k) {
        int s = k * 64 + lane;
        unsigned nib = (unsigned)((lds.es.smask[s] >> p0) & 15ull);
        double wv = (double)lds.es.swq[s];
        int i = start + k;
#pragma unroll
        for (int q = 0; q < 4; ++q) {
            running[q] += ((nib >> q) & 1u) ? wv * norm[q] : -inv_denom[q];
            double a = fabs(running[q]);
            if (a > bestv[q]) { bestv[q] = a; bestr[q] = running[q]; besti[q] = i; }
        }
    }
#pragma unroll
    for (int q = 0; q < 4; ++q) {
#pragma unroll
        for (int off = 1; off < 64; off <<= 1) {
            double ov  = __shfl_xor(bestv[q], off, 64);
            double orr = __shfl_xor(bestr[q], off, 64);
            int    oi  = __shfl_xor(besti[q], off, 64);
            if (ov > bestv[q] || (ov == bestv[q] && oi < besti[q])) {
                bestv[q] = ov; bestr[q] = orr; besti[q] = oi;
            }
        }
    }

    if (lane == 0) {
#pragma unroll
        for (int q = 0; q < 4; ++q) {
            int p = p0 + q;
            if (p < P)
                out[(size_t)b * P + p] = (sht[q] > 0) ? (float)bestr[q] : 0.0f;
        }
    }
}

extern "C" void kernel_launch(void* const* d_in, const int* in_sizes, int n_in,
                              void* d_out, int out_size, void* d_ws, size_t ws_size,
                              hipStream_t stream) {
    const float* expr    = (const float*)d_in[0];   // [B, G]
    const float* pathway = (const float*)d_in[1];   // [P, G]
    float* out = (float*)d_out;                     // [B, P]

    // workspace: per-block private pbits copies: ull[B][SLOTS] = ~2.6 MB
    ull* pball = (ull*)d_ws;

    fused_kernel<<<dim3(Bc), dim3(SORT_T), 0, stream>>>(
        expr, pathway, pball, out, Bc, Pc, Gc);
}

// Round 7
// 128.679 us; speedup vs baseline: 1.3667x; 1.3667x over previous
//
#include <hip/hip_runtime.h>
#include <math.h>

typedef unsigned long long ull;

// Problem constants (from setup_inputs): B=64, G=4999, P=50
constexpr int Bc = 64;
constexpr int Gc = 4999;
constexpr int Pc = 50;

constexpr int RUN   = 512;           // elements per sorted run (one wave)
constexpr int NRUN  = 10;            // runs per row (10*512 = 5120 >= G)
constexpr int NPAD  = NRUN * RUN;
constexpr int EPT   = 8;             // sort elements per lane (16 VGPRs)
constexpr int LPW   = 79;            // genes per lane in es phase
constexpr int SLOTS = 5056;          // 79*64 chunk-major slots
constexpr ull PADKEY = 0xFFFFFFFFFFFFFFFFull;

__device__ __forceinline__ ull shfl_xor64(ull v, int lm) {
    int lo = __shfl_xor((int)(unsigned)(v & 0xFFFFFFFFull), lm, 64);
    int hi = __shfl_xor((int)(unsigned)(v >> 32), lm, 64);
    return ((ull)(unsigned)hi << 32) | (unsigned)lo;
}

// ---------------------------------------------------------------------------
// Kernel 1: one WAVE sorts one 512-element run in registers + shuffles only.
// key = (~m)<<32 | idx (unique): ascending u64 == descending value, stable by
// original index (== stable argsort(-x)). 8 elems/lane: j>=8 stages via
// shfl_xor (lm = j/8 <= 32, intra-wave), j<=4 in-register. No LDS, no
// barriers. Grid (2,64) x 320 thr: block (rg,b) sorts runs rg*5..rg*5+4.
// Blocks with rg==0 also pack pathway bits (consumed by next launch — safe).
// ---------------------------------------------------------------------------
__global__ __launch_bounds__(320) void wave_sort512(
    const float* __restrict__ expr, const float* __restrict__ pathway,
    ull* __restrict__ runs, ull* __restrict__ pbits, int P, int G)
{
    const int rg = blockIdx.x, b = blockIdx.y;
    const int tid = threadIdx.x;
    const int lane = tid & 63;
    const int w = tid >> 6;              // 0..4
    const int r = rg * 5 + w;            // run id 0..9
    const int base = lane * EPT;         // position within run
    const float* row = expr + (size_t)b * G;

    ull v[EPT];
#pragma unroll
    for (int o = 0; o < EPT; ++o) {
        int i = r * RUN + base + o;
        if (i < G) {
            unsigned u = __float_as_uint(row[i]);
            unsigned m = (u >> 31) ? ~u : (u | 0x80000000u);  // monotone map
            v[o] = ((ull)(~m) << 32) | (unsigned)i;
        } else {
            v[o] = PADKEY;
        }
    }

#pragma unroll
    for (int kk = 2; kk <= RUN; kk <<= 1) {
        // shuffle stages: j = kk/2 .. 8 (partner = lane ^ (j/8), intra-wave)
#pragma unroll
        for (int j = kk >> 1; j >= EPT; j >>= 1) {
            const int lm = j >> 3;
            const bool takeMin = (((lane & lm) == 0) == ((base & kk) == 0));
#pragma unroll
            for (int o = 0; o < EPT; ++o) {
                ull c = shfl_xor64(v[o], lm);
                ull mn = (v[o] < c) ? v[o] : c;
                ull mx = (v[o] < c) ? c : v[o];
                v[o] = takeMin ? mn : mx;
            }
        }
        // register stages: j = 4, 2, 1
#pragma unroll
        for (int j = 4; j >= 1; j >>= 1) {
            if (j < kk) {
#pragma unroll
                for (int o = 0; o < EPT; ++o) {
                    if ((o & j) == 0) {
                        bool up = (((base + o) & kk) == 0);
                        ull a = v[o], c = v[o | j];
                        if ((a > c) == up) { v[o] = c; v[o | j] = a; }
                    }
                }
            }
        }
    }

    ull* dst = runs + ((size_t)b * NRUN + r) * RUN;
#pragma unroll
    for (int o = 0; o < EPT; ++o) dst[base + o] = v[o];

    // Folded pack: rg==0 blocks (64 x 320 = 20480 threads >= G), g unique.
    if (rg == 0) {
        int g = b * 320 + tid;
        if (g < G) {
            ull m = 0;
#pragma unroll
            for (int p = 0; p < Pc; ++p)
                if (pathway[(size_t)p * G + g] > 0.0f) m |= (1ull << p);
            pbits[g] = m;
        }
    }
}

// ---------------------------------------------------------------------------
// Kernel 2: fused rank + es. Grid (2,64) x 1024: block (hb,b) handles sample
// b, pathways [hb*25, hb*25+25). Stage 10 sorted runs in LDS; each thread
// ranks 5 elements (own-run pos + 9 binary searches, exact bijection onto
// [0,G) since keys are unique); barrier; overwrite LDS union with chunk-major
// swq/smask (slot = (rank%79)*64 + rank/79 -> conflict-free es reads);
// es: wave w handles 4 pathways in one pass over its 79-gene chunk.
// ---------------------------------------------------------------------------
__global__ __launch_bounds__(1024) void rank_es(
    const ull* __restrict__ runs, const ull* __restrict__ pbits,
    float* __restrict__ out, int B, int P, int G)
{
    __shared__ union {
        ull runsLDS[NPAD];                                   // 40960 B
        struct { ull smask[SLOTS]; float swq[SLOTS]; } es;   // 60672 B
    } lds;

    const int hb = blockIdx.x;      // pathway half: 0 or 1
    const int b  = blockIdx.y;
    const int tid = threadIdx.x;

    // ---- Stage all 10 runs (coalesced) ----
    const ull* rowruns = runs + (size_t)b * NPAD;
    for (int i = tid; i < NPAD; i += 1024) lds.runsLDS[i] = rowruns[i];
    __syncthreads();

    // ---- Rank 5 elements per thread ----
    int rankv[5];
    ull keyv_[5];
#pragma unroll
    for (int o = 0; o < 5; ++o) {
        const int e = o * 1024 + tid;          // 0..5119
        const ull keyv = lds.runsLDS[e];
        keyv_[o] = keyv;
        if (keyv == PADKEY) { rankv[o] = -1; continue; }
        const int run = e >> 9;                // e / 512
        int rank = e & 511;                    // own-run position (stable)
#pragma unroll
        for (int rr = 0; rr < NRUN; ++rr) {
            if (rr == run) continue;
            const ull* arr = &lds.runsLDS[rr * RUN];
            int pos = 0;
#pragma unroll
            for (int s = RUN; s >= 1; s >>= 1) {
                int np = pos + s;
                if (np <= RUN && arr[np - 1] < keyv) pos = np;
            }
            rank += pos;                       // # elements < keyv
        }
        rankv[o] = rank;
    }
    __syncthreads();   // done reading runsLDS before union overwrite

    // ---- Scatter chunk-major swq/smask ----
#pragma unroll
    for (int o = 0; o < 5; ++o) {
        if (rankv[o] < 0) continue;
        const ull k = keyv_[o];
        int idx = (int)(unsigned)(k & 0xFFFFFFFFu);
        unsigned m = ~((unsigned)(k >> 32));
        unsigned absbits = ((m >> 31) ? m : ~m) & 0x7FFFFFFFu;
        float av = __uint_as_float(absbits);
        const int rank = rankv[o];
        const int slot = (rank % LPW) * 64 + (rank / LPW);
        lds.es.swq[slot]   = sqrtf(sqrtf(av));   // |v|^0.25
        lds.es.smask[slot] = pbits[idx];         // L2-hot random gather
    }
    __syncthreads();

    // ---- es phase: wave w -> pathways p0..p0+3 within [pbeg, pend) ----
    const int lane = tid & 63;
    const int w = tid >> 6;
    const int pbeg = hb * 25, pend = (hb == 0) ? 25 : P;
    const int p0 = pbeg + w * 4;
    if (p0 >= pend) return;

    const int start = lane * LPW;
    const int cnt = (start + LPW < G) ? LPW : (G - start);

    // Pass A: per-chunk (sum w*hit, #hit) for 4 pathways at once
    double sw[4] = {0.0, 0.0, 0.0, 0.0};
    int sh[4] = {0, 0, 0, 0};
    for (int k = 0; k < cnt; ++k) {
        int s = k * 64 + lane;
        unsigned nib = (unsigned)((lds.es.smask[s] >> p0) & 15ull);
        double wv = (double)lds.es.swq[s];
#pragma unroll
        for (int q = 0; q < 4; ++q) {
            if ((nib >> q) & 1u) { sw[q] += wv; sh[q]++; }
        }
    }
    double norm[4], inv_denom[4], running[4];
    int sht[4];
#pragma unroll
    for (int q = 0; q < 4; ++q) {
        double swt = sw[q];
        int shq = sh[q];
#pragma unroll
        for (int off = 1; off < 64; off <<= 1) {
            swt += __shfl_xor(swt, off, 64);
            shq += __shfl_xor(shq, off, 64);
        }
        sht[q] = shq;
        norm[q]      = (swt > 0.0) ? 1.0 / swt : 1.0;
        inv_denom[q] = 1.0 / fmax((double)(G - shq), 1.0);
        double csum = sw[q] * norm[q] - (double)(cnt - sh[q]) * inv_denom[q];
        double x = csum;
#pragma unroll
        for (int off = 1; off < 64; off <<= 1) {
            double vv = __shfl_up(x, off, 64);
            if (lane >= off) x += vv;
        }
        running[q] = x - csum;     // exclusive prefix for this chunk
    }

    // Pass C: walk chunk, first-occurrence argmax of |running| (4 pathways)
    double bestv[4] = {-1.0, -1.0, -1.0, -1.0};
    double bestr[4] = {0.0, 0.0, 0.0, 0.0};
    int besti[4] = {0x7FFFFFFF, 0x7FFFFFFF, 0x7FFFFFFF, 0x7FFFFFFF};
    for (int k = 0; k < cnt; ++k) {
        int s = k * 64 + lane;
        unsigned nib = (unsigned)((lds.es.smask[s] >> p0) & 15ull);
        double wv = (double)lds.es.swq[s];
        int i = start + k;
#pragma unroll
        for (int q = 0; q < 4; ++q) {
            running[q] += ((nib >> q) & 1u) ? wv * norm[q] : -inv_denom[q];
            double a = fabs(running[q]);
            if (a > bestv[q]) { bestv[q] = a; bestr[q] = running[q]; besti[q] = i; }
        }
    }
#pragma unroll
    for (int q = 0; q < 4; ++q) {
#pragma unroll
        for (int off = 1; off < 64; off <<= 1) {
            double ov  = __shfl_xor(bestv[q], off, 64);
            double orr = __shfl_xor(bestr[q], off, 64);
            int    oi  = __shfl_xor(besti[q], off, 64);
            if (ov > bestv[q] || (ov == bestv[q] && oi < besti[q])) {
                bestv[q] = ov; bestr[q] = orr; besti[q] = oi;
            }
        }
    }

    if (lane == 0) {
#pragma unroll
        for (int q = 0; q < 4; ++q) {
            int p = p0 + q;
            if (p < pend)
                out[(size_t)b * P + p] = (sht[q] > 0) ? (float)bestr[q] : 0.0f;
        }
    }
}

extern "C" void kernel_launch(void* const* d_in, const int* in_sizes, int n_in,
                              void* d_out, int out_size, void* d_ws, size_t ws_size,
                              hipStream_t stream) {
    const float* expr    = (const float*)d_in[0];   // [B, G]
    const float* pathway = (const float*)d_in[1];   // [P, G]
    float* out = (float*)d_out;                     // [B, P]

    // workspace layout (bytes):
    //   pbits ull[G]        @ 0        (40960 reserved)
    //   runs  ull[B*NPAD]   @ 40960    (2621440)   total ~2.7 MB
    char* ws = (char*)d_ws;
    ull* pbits = (ull*)ws;
    ull* runs  = (ull*)(ws + 40960);

    wave_sort512<<<dim3(2, Bc), dim3(320), 0, stream>>>(
        expr, pathway, runs, pbits, Pc, Gc);
    rank_es<<<dim3(2, Bc), dim3(1024), 0, stream>>>(
        runs, pbits, out, Bc, Pc, Gc);
}

// Round 8
// 112.084 us; speedup vs baseline: 1.5690x; 1.1481x over previous
//
#include <hip/hip_runtime.h>
#include <math.h>

typedef unsigned long long ull;

// Problem constants (from setup_inputs): B=64, G=4999, P=50
constexpr int Bc = 64;
constexpr int Gc = 4999;
constexpr int Pc = 50;

constexpr int RUN   = 512;           // elements per sorted run (one wave)
constexpr int NRUN  = 10;            // runs per row (10*512 = 5120 >= G)
constexpr int NPAD  = NRUN * RUN;
constexpr int EPT   = 8;             // sort elements per lane (16 VGPRs)
constexpr int LPW   = 79;            // genes per lane in es phase
constexpr ull PADKEY = 0xFFFFFFFFFFFFFFFFull;

__device__ __forceinline__ ull shfl_xor64(ull v, int lm) {
    int lo = __shfl_xor((int)(unsigned)(v & 0xFFFFFFFFull), lm, 64);
    int hi = __shfl_xor((int)(unsigned)(v >> 32), lm, 64);
    return ((ull)(unsigned)hi << 32) | (unsigned)lo;
}

// ---------------------------------------------------------------------------
// Kernel 1: one WAVE sorts one 512-element run in registers + shuffles only.
// key = (~m)<<32 | idx (unique): ascending u64 == descending value, stable by
// original index (== stable argsort(-x)). Proven in round 7.
// Blocks with rg==0 also pack pathway bits (consumed by next launch — safe).
// ---------------------------------------------------------------------------
__global__ __launch_bounds__(320) void wave_sort512(
    const float* __restrict__ expr, const float* __restrict__ pathway,
    ull* __restrict__ runs, ull* __restrict__ pbits, int P, int G)
{
    const int rg = blockIdx.x, b = blockIdx.y;
    const int tid = threadIdx.x;
    const int lane = tid & 63;
    const int w = tid >> 6;              // 0..4
    const int r = rg * 5 + w;            // run id 0..9
    const int base = lane * EPT;
    const float* row = expr + (size_t)b * G;

    ull v[EPT];
#pragma unroll
    for (int o = 0; o < EPT; ++o) {
        int i = r * RUN + base + o;
        if (i < G) {
            unsigned u = __float_as_uint(row[i]);
            unsigned m = (u >> 31) ? ~u : (u | 0x80000000u);  // monotone map
            v[o] = ((ull)(~m) << 32) | (unsigned)i;
        } else {
            v[o] = PADKEY;
        }
    }

#pragma unroll
    for (int kk = 2; kk <= RUN; kk <<= 1) {
#pragma unroll
        for (int j = kk >> 1; j >= EPT; j >>= 1) {
            const int lm = j >> 3;
            const bool takeMin = (((lane & lm) == 0) == ((base & kk) == 0));
#pragma unroll
            for (int o = 0; o < EPT; ++o) {
                ull c = shfl_xor64(v[o], lm);
                ull mn = (v[o] < c) ? v[o] : c;
                ull mx = (v[o] < c) ? c : v[o];
                v[o] = takeMin ? mn : mx;
            }
        }
#pragma unroll
        for (int j = 4; j >= 1; j >>= 1) {
            if (j < kk) {
#pragma unroll
                for (int o = 0; o < EPT; ++o) {
                    if ((o & j) == 0) {
                        bool up = (((base + o) & kk) == 0);
                        ull a = v[o], c = v[o | j];
                        if ((a > c) == up) { v[o] = c; v[o | j] = a; }
                    }
                }
            }
        }
    }

    ull* dst = runs + ((size_t)b * NRUN + r) * RUN;
#pragma unroll
    for (int o = 0; o < EPT; ++o) dst[base + o] = v[o];

    if (rg == 0) {
        int g = b * 320 + tid;
        if (g < G) {
            ull m = 0;
#pragma unroll
            for (int p = 0; p < Pc; ++p)
                if (pathway[(size_t)p * G + g] > 0.0f) m |= (1ull << p);
            pbits[g] = m;
        }
    }
}

// ---------------------------------------------------------------------------
// Kernel 2: rank + scatter, NO duplication. Grid (5,64) x 1024: block (rg,b)
// stages all 10 runs (40 KB LDS) and ranks elements [rg*1024, rg*1024+1024),
// one per thread: rank = own-run pos + 9 binary searches (exact bijection onto
// [0,G), keys unique). Writes wq (|v|^0.25 decoded from key) and mask
// (pbits[gene] pre-permuted into sorted order) to global.
// ---------------------------------------------------------------------------
__global__ __launch_bounds__(1024) void rank_scatter(
    const ull* __restrict__ runs, const ull* __restrict__ pbits,
    float* __restrict__ wqout, ull* __restrict__ maskout, int G)
{
    __shared__ ull runsLDS[NPAD];   // 40960 B
    const int rg = blockIdx.x, b = blockIdx.y, tid = threadIdx.x;

    const ull* rowruns = runs + (size_t)b * NPAD;
    for (int i = tid; i < NPAD; i += 1024) runsLDS[i] = rowruns[i];
    __syncthreads();

    const int e = rg * 1024 + tid;          // 0..5119
    const ull keyv = runsLDS[e];
    if (keyv == PADKEY) return;             // padding

    const int run = e >> 9;                 // e / 512
    int rank = e & 511;                     // own-run position (stable)
#pragma unroll
    for (int rr = 0; rr < NRUN; ++rr) {
        if (rr == run) continue;
        const ull* arr = &runsLDS[rr * RUN];
        int pos = 0;
#pragma unroll
        for (int s = RUN; s >= 1; s >>= 1) {
            int np = pos + s;
            if (np <= RUN && arr[np - 1] < keyv) pos = np;
        }
        rank += pos;                        // # elements < keyv
    }

    int idx = (int)(unsigned)(keyv & 0xFFFFFFFFu);
    unsigned m = ~((unsigned)(keyv >> 32));
    unsigned absbits = ((m >> 31) ? m : ~m) & 0x7FFFFFFFu;
    float av = __uint_as_float(absbits);
    wqout[(size_t)b * G + rank] = sqrtf(sqrtf(av));   // |v|^0.25
    maskout[(size_t)b * G + rank] = pbits[idx];
}

// ---------------------------------------------------------------------------
// Kernel 3: enrichment scores, full-GPU shape. Grid (4,64) x 256 thr: block
// (pg,b) handles sample b, pathways [pg*13, min(pg*13+13, P)). Stages swq
// (f32) + a pre-shifted u32 mask slice (mask >> pbeg; 13 bits used) -> 40 KB
// LDS, all b32 accesses (stride-79 reads: 79 mod 32 = 15 coprime with 32 ->
// conflict-free). Wave w computes 4 pathways in one pass over its 79 genes.
// ---------------------------------------------------------------------------
__global__ __launch_bounds__(256) void es_kernel(
    const float* __restrict__ wq, const ull* __restrict__ mask,
    float* __restrict__ out, int B, int P, int G)
{
    __shared__ float    swq[Gc];    // 19996 B
    __shared__ unsigned sm32[Gc];   // 19996 B  (~40 KB)

    const int pg = blockIdx.x;
    const int b  = blockIdx.y;
    const int tid = threadIdx.x;
    const int pbeg = pg * 13;
    const int pend = (pbeg + 13 < P) ? (pbeg + 13) : P;

    for (int i = tid; i < G; i += 256) {
        swq[i]  = wq[(size_t)b * G + i];
        sm32[i] = (unsigned)(mask[(size_t)b * G + i] >> pbeg);
    }
    __syncthreads();

    const int lane = tid & 63;
    const int w = tid >> 6;
    const int p0 = pbeg + w * 4;
    if (p0 >= pend) return;
    const int sh4 = w * 4;                 // shift within the u32 slice

    const int start = lane * LPW;
    const int cnt = (start + LPW < G) ? LPW : (G - start);

    // Pass A: per-chunk (sum w*hit, #hit) for 4 pathways at once
    double sw[4] = {0.0, 0.0, 0.0, 0.0};
    int sh[4] = {0, 0, 0, 0};
    for (int k = 0; k < cnt; ++k) {
        int s = start + k;
        unsigned nib = (sm32[s] >> sh4) & 15u;
        double wv = (double)swq[s];
#pragma unroll
        for (int q = 0; q < 4; ++q) {
            if ((nib >> q) & 1u) { sw[q] += wv; sh[q]++; }
        }
    }
    double norm[4], inv_denom[4], running[4];
    int sht[4];
#pragma unroll
    for (int q = 0; q < 4; ++q) {
        double swt = sw[q];
        int shq = sh[q];
#pragma unroll
        for (int off = 1; off < 64; off <<= 1) {
            swt += __shfl_xor(swt, off, 64);
            shq += __shfl_xor(shq, off, 64);
        }
        sht[q] = shq;
        norm[q]      = (swt > 0.0) ? 1.0 / swt : 1.0;
        inv_denom[q] = 1.0 / fmax((double)(G - shq), 1.0);
        double csum = sw[q] * norm[q] - (double)(cnt - sh[q]) * inv_denom[q];
        double x = csum;
#pragma unroll
        for (int off = 1; off < 64; off <<= 1) {
            double vv = __shfl_up(x, off, 64);
            if (lane >= off) x += vv;
        }
        running[q] = x - csum;     // exclusive prefix for this chunk
    }

    // Pass C: walk chunk, first-occurrence argmax of |running| (4 pathways)
    double bestv[4] = {-1.0, -1.0, -1.0, -1.0};
    double bestr[4] = {0.0, 0.0, 0.0, 0.0};
    int besti[4] = {0x7FFFFFFF, 0x7FFFFFFF, 0x7FFFFFFF, 0x7FFFFFFF};
    for (int k = 0; k < cnt; ++k) {
        int s = start + k;
        unsigned nib = (sm32[s] >> sh4) & 15u;
        double wv = (double)swq[s];
        int i = start + k;
#pragma unroll
        for (int q = 0; q < 4; ++q) {
            running[q] += ((nib >> q) & 1u) ? wv * norm[q] : -inv_denom[q];
            double a = fabs(running[q]);
            if (a > bestv[q]) { bestv[q] = a; bestr[q] = running[q]; besti[q] = i; }
        }
    }
#pragma unroll
    for (int q = 0; q < 4; ++q) {
#pragma unroll
        for (int off = 1; off < 64; off <<= 1) {
            double ov  = __shfl_xor(bestv[q], off, 64);
            double orr = __shfl_xor(bestr[q], off, 64);
            int    oi  = __shfl_xor(besti[q], off, 64);
            if (ov > bestv[q] || (ov == bestv[q] && oi < besti[q])) {
                bestv[q] = ov; bestr[q] = orr; besti[q] = oi;
            }
        }
    }

    if (lane == 0) {
#pragma unroll
        for (int q = 0; q < 4; ++q) {
            int p = p0 + q;
            if (p < pend)
                out[(size_t)b * P + p] = (sht[q] > 0) ? (float)bestr[q] : 0.0f;
        }
    }
}

extern "C" void kernel_launch(void* const* d_in, const int* in_sizes, int n_in,
                              void* d_out, int out_size, void* d_ws, size_t ws_size,
                              hipStream_t stream) {
    const float* expr    = (const float*)d_in[0];   // [B, G]
    const float* pathway = (const float*)d_in[1];   // [P, G]
    float* out = (float*)d_out;                     // [B, P]

    // workspace layout (bytes):
    //   pbits ull[G]        @ 0        (40960 reserved)
    //   runs  ull[B*NPAD]   @ 40960    (2621440)
    //   wq    f32[B*G]      @ 2662400  (1279744)
    //   mask  ull[B*G]      @ 3942144  (2559488)   total ~6.5 MB
    char* ws = (char*)d_ws;
    ull*   pbits = (ull*)ws;
    ull*   runs  = (ull*)(ws + 40960);
    float* wqa   = (float*)(ws + 2662400);
    ull*   maska = (ull*)(ws + 3942144);

    wave_sort512<<<dim3(2, Bc), dim3(320), 0, stream>>>(
        expr, pathway, runs, pbits, Pc, Gc);
    rank_scatter<<<dim3(5, Bc), dim3(1024), 0, stream>>>(runs, pbits, wqa, maska, Gc);
    es_kernel<<<dim3(4, Bc), dim3(256), 0, stream>>>(wqa, maska, out, Bc, Pc, Gc);
}